// Round 6
// baseline (602.099 us; speedup 1.0000x reference)
//
#include <hip/hip_runtime.h>

#define N_NODES 65536
#define N_EDGES 1048576
#define NB      512

typedef unsigned short u16;
typedef unsigned int   u32;
typedef unsigned long long u64;

typedef __attribute__((ext_vector_type(8))) short bf16x8;
typedef __attribute__((ext_vector_type(4))) float f32x4;

__device__ __forceinline__ float bf2f(u16 u) { return __uint_as_float(((u32)u) << 16); }
__device__ __forceinline__ float lo16(u32 u) { return __uint_as_float(u << 16); }
__device__ __forceinline__ float hi16(u32 u) { return __uint_as_float(u & 0xffff0000u); }
__device__ __forceinline__ u16 f2bf(float f) {
    u32 u = __float_as_uint(f);
    u32 r = (u + 0x7fffu + ((u >> 16) & 1u)) >> 16;
    return (u16)r;
}
__device__ __forceinline__ u32 pk2(float a, float b) {
    return (u32)f2bf(a) | ((u32)f2bf(b) << 16);
}
__device__ __forceinline__ float wsum(float v) {
    for (int o = 32; o; o >>= 1) v += __shfl_xor(v, o, 64);
    return v;
}
__device__ __forceinline__ float wmax(float v) {
    for (int o = 32; o; o >>= 1) v = fmaxf(v, __shfl_xor(v, o, 64));
    return v;
}

// ---------- mega prep: all weight transposes + M1/M2 in one launch ----------
__global__ __launch_bounds__(512) void k_wprep(const float* __restrict__ g1W, const float* __restrict__ roiW,
                                               const float* __restrict__ g2W,
                                               const float* __restrict__ g1We, const float* __restrict__ g1ae,
                                               const float* __restrict__ g2We, const float* __restrict__ g2ae,
                                               u16* __restrict__ g1Wt, u16* __restrict__ roiWt,
                                               u16* __restrict__ g2Wt, float* __restrict__ M1,
                                               float* __restrict__ M2) {
    int b = blockIdx.x, t = threadIdx.x;
    if (b < 48) {
        int idx = b * 512 + t;          // 0..24575 = 256*96
        int c = idx / 96, k = idx - 96 * c;
        float v = 0.f;
        if (k < 77) {
            int ko = (k < 64) ? (13 + k) : (k - 64);
            v = g1W[(size_t)ko * 256 + c];
        }
        g1Wt[idx] = f2bf(v);
    } else if (b < 80) {
        int idx = (b - 48) * 512 + t;   // 0..16383 = 64*256
        int c = idx >> 8, k = idx & 255;
        roiWt[idx] = f2bf(roiW[(size_t)k * 64 + c]);
    } else if (b < 112) {
        int idx = (b - 80) * 512 + t;
        int c = idx >> 8, k = idx & 255;
        g2Wt[idx] = f2bf(g2W[(size_t)k * 64 + c]);
    } else {
        if (t < 20) {
            int j = t >> 2, h = t & 3;
            float s = 0.f;
            for (int c = 0; c < 64; c++) s += g1We[j * 256 + h * 64 + c] * g1ae[h * 64 + c];
            M1[t] = s;
        } else if (t < 25) {
            int j = t - 20;
            float s = 0.f;
            for (int c = 0; c < 64; c++) s += g2We[j * 64 + c] * g2ae[c];
            M2[j] = s;
        }
    }
}

// ---------- scene ----------
__global__ __launch_bounds__(256) void k_scene(const float* __restrict__ gf, const float* __restrict__ W,
                                               const float* __restrict__ bias, float* __restrict__ scene) {
    int idx = blockIdx.x * 256 + threadIdx.x;
    int b = idx >> 7, j = idx & 127;
    float acc = 0.f;
    for (int k = 0; k < 512; k++) acc += gf[b * 512 + k] * W[k * 128 + j];
    scene[idx] = acc + bias[j];
}

// ---------- histogram ----------
__global__ __launch_bounds__(256) void k_hist(const int* ei, int* cnt) {
    int e = blockIdx.x * 256 + threadIdx.x;
    atomicAdd(&cnt[ei[N_EDGES + e]], 1);
}

// ---------- hierarchical exclusive scan ----------
__global__ __launch_bounds__(256) void k_scan_blk(const int* __restrict__ cnt, int* __restrict__ pre,
                                                  int* __restrict__ bsum) {
    __shared__ int sd[256];
    int t = threadIdx.x, b = blockIdx.x;
    int base = b * 1024 + t * 4;
    int4 c = *(const int4*)(cnt + base);
    int s = c.x + c.y + c.z + c.w;
    sd[t] = s;
    __syncthreads();
    for (int off = 1; off < 256; off <<= 1) {
        int v = (t >= off) ? sd[t - off] : 0;
        __syncthreads();
        sd[t] += v;
        __syncthreads();
    }
    int excl = sd[t] - s;
    int4 p;
    p.x = excl;
    p.y = excl + c.x;
    p.z = excl + c.x + c.y;
    p.w = excl + c.x + c.y + c.z;
    *(int4*)(pre + base) = p;
    if (t == 255) bsum[b] = sd[255];
}

__global__ __launch_bounds__(64) void k_scan_top(int* bsum) {
    int t = threadIdx.x;
    int v = bsum[t];
    int inc = v;
    for (int off = 1; off < 64; off <<= 1) {
        int u = __shfl_up(inc, off, 64);
        if (t >= off) inc += u;
    }
    bsum[t] = inc - v;
}

__global__ __launch_bounds__(256) void k_scan_fix(const int* __restrict__ pre, const int* __restrict__ bsum,
                                                  int* __restrict__ row_ptr, int* __restrict__ coarse_cur) {
    int i = blockIdx.x * 256 + threadIdx.x;
    int v = pre[i] + bsum[i >> 10];
    row_ptr[i] = v;
    if ((i & 255) == 0) coarse_cur[i >> 8] = v;
    if (i == 0) row_ptr[N_NODES] = N_EDGES;
}

// ---------- bucket pass (R2-proven shape: 256 blocks x 4096 edges) ----------
__global__ __launch_bounds__(256) void k_bucket(const int* __restrict__ ei, int* coarse_cur,
                                                u32* __restrict__ bpack, int* __restrict__ bsrc) {
    __shared__ u32 stageP[4096];
    __shared__ int stageS[4096];
    __shared__ int bcnt[256], bscan[256], boff[256], gbase[256];
    int t = threadIdx.x;
    int e0 = blockIdx.x * 4096;
    bcnt[t] = 0;
    __syncthreads();
    int dreg[16], sreg[16];
    for (int it = 0; it < 16; it++) {
        int e = e0 + it * 256 + t;
        int dd = ei[N_EDGES + e];
        dreg[it] = dd;
        sreg[it] = ei[e];
        atomicAdd(&bcnt[dd >> 8], 1);
    }
    __syncthreads();
    int v = bcnt[t];
    bscan[t] = v;
    __syncthreads();
    for (int off = 1; off < 256; off <<= 1) {
        int u = (t >= off) ? bscan[t - off] : 0;
        __syncthreads();
        bscan[t] += u;
        __syncthreads();
    }
    boff[t] = bscan[t] - v;
    gbase[t] = v ? atomicAdd(&coarse_cur[t], v) : 0;
    __syncthreads();
    for (int it = 0; it < 16; it++) {
        int e = e0 + it * 256 + t;
        int b = dreg[it] >> 8;
        int pos = atomicAdd(&boff[b], 1);
        stageP[pos] = ((u32)e << 12) | (u32)(dreg[it] & 255);
        stageS[pos] = sreg[it];
    }
    __syncthreads();
    for (int idx = t; idx < 4096; idx += 256) {
        int lo = 0, hi = 255;
        while (lo < hi) { int mid = (lo + hi) >> 1; if (bscan[mid] > idx) hi = mid; else lo = mid + 1; }
        int b = lo;
        int g = gbase[b] + (idx - (bscan[b] - bcnt[b]));
        bpack[g] = stageP[idx];
        bsrc[g] = stageS[idx];
    }
}

// ---------- local sort within bucket, fused with payload ----------
__global__ __launch_bounds__(256) void k_sortp(const u32* __restrict__ bpack, const int* __restrict__ bsrc,
                                               const int* __restrict__ row_ptr, const float* __restrict__ ea,
                                               const float* __restrict__ M1, const float* __restrict__ M2,
                                               int* __restrict__ ssrc, float* __restrict__ a1es,
                                               float* __restrict__ a2es) {
    __shared__ int cur[256];
    int t = threadIdx.x, b = blockIdx.x;
    int nbase = b * 256;
    cur[t] = row_ptr[nbase + t];
    __syncthreads();
    float m1[20], m2[5];
    #pragma unroll
    for (int j = 0; j < 20; j++) m1[j] = M1[j];
    #pragma unroll
    for (int j = 0; j < 5; j++) m2[j] = M2[j];
    int beg = row_ptr[nbase];
    int end = row_ptr[nbase + 256];
    for (int i = beg + t; i < end; i += 256) {
        u32 wd = bpack[i];
        int src = bsrc[i];
        int d8 = wd & 255;
        int e = (int)(wd >> 12);
        int pos = atomicAdd(&cur[d8], 1);
        ssrc[pos] = src;
        const float* ep = ea + (size_t)e * 5;
        float v0 = ep[0], v1 = ep[1], v2 = ep[2], v3 = ep[3], v4 = ep[4];
        float4 o;
        o.x = v0*m1[0]  + v1*m1[4]  + v2*m1[8]  + v3*m1[12] + v4*m1[16];
        o.y = v0*m1[1]  + v1*m1[5]  + v2*m1[9]  + v3*m1[13] + v4*m1[17];
        o.z = v0*m1[2]  + v1*m1[6]  + v2*m1[10] + v3*m1[14] + v4*m1[18];
        o.w = v0*m1[3]  + v1*m1[7]  + v2*m1[11] + v3*m1[15] + v4*m1[19];
        *(float4*)(a1es + (size_t)pos * 4) = o;
        a2es[pos] = v0*m2[0] + v1*m2[1] + v2*m2[2] + v3*m2[3] + v4*m2[4];
    }
}

// ---------- fused vis+h1: vis = relu(roi@roiW+b) -> LDS only; h1 = [vis|x]@g1Wt + a1s/a1d ----------
__global__ __launch_bounds__(256) void k_vh(const float* __restrict__ roi, const u16* __restrict__ WtV,
                                            const float* __restrict__ visb, const float* __restrict__ x,
                                            const u16* __restrict__ Wt1,
                                            const float* __restrict__ as_, const float* __restrict__ ad_,
                                            u16* __restrict__ h1, float* __restrict__ a1s,
                                            float* __restrict__ a1d) {
    __shared__ u16 At[64][264];   // roi staged bf16 (K=256)
    __shared__ u16 A1[64][104];   // [vis(64) | x(13) | 0..] staged bf16 (K'=96)
    int t = threadIdx.x;
    int w = t >> 6, l = t & 63, lo = l & 15, hi = l >> 4;
    int n0 = blockIdx.x * 64;
    int r = t >> 2, sub = t & 3;
    // stage roi -> At
    const float* rp = roi + (size_t)(n0 + r) * 256 + sub * 4;
    #pragma unroll
    for (int q = 0; q < 16; q++) {
        float4 v = *(const float4*)(rp + q * 16);
        uint2 p;
        p.x = pk2(v.x, v.y);
        p.y = pk2(v.z, v.w);
        *(uint2*)&At[r][q * 16 + sub * 4] = p;
    }
    // x part + zero pad into A1 (independent of vis)
    if (sub == 0) {
        const float* xp = x + (size_t)(n0 + r) * 13;
        #pragma unroll
        for (int j = 0; j < 13; j++) A1[r][64 + j] = f2bf(xp[j]);
    } else if (sub == 1) {
        #pragma unroll
        for (int j = 77; j < 96; j++) A1[r][j] = 0;
    }
    float bb[4][4];
    #pragma unroll
    for (int cb = 0; cb < 4; cb++)
        #pragma unroll
        for (int rg = 0; rg < 4; rg++) bb[cb][rg] = visb[cb * 16 + hi * 4 + rg];
    __syncthreads();
    // ---- vis MFMA (wave w: nodes w*16+lo, all 64 ch) ----
    {
        f32x4 acc[4];
        #pragma unroll
        for (int cb = 0; cb < 4; cb++) acc[cb] = (f32x4){0.f, 0.f, 0.f, 0.f};
        #pragma unroll
        for (int ks = 0; ks < 8; ks++) {
            bf16x8 af = *(const bf16x8*)(&At[w * 16 + lo][ks * 32 + hi * 8]);
            #pragma unroll
            for (int cb = 0; cb < 4; cb++) {
                bf16x8 wf = *(const bf16x8*)(WtV + (size_t)(cb * 16 + lo) * 256 + ks * 32 + hi * 8);
                acc[cb] = __builtin_amdgcn_mfma_f32_16x16x32_bf16(wf, af, acc[cb], 0, 0, 0);
            }
        }
        #pragma unroll
        for (int cb = 0; cb < 4; cb++) {
            uint2 p;
            p.x = pk2(fmaxf(acc[cb][0] + bb[cb][0], 0.f), fmaxf(acc[cb][1] + bb[cb][1], 0.f));
            p.y = pk2(fmaxf(acc[cb][2] + bb[cb][2], 0.f), fmaxf(acc[cb][3] + bb[cb][3], 0.f));
            *(uint2*)&A1[w * 16 + lo][cb * 16 + hi * 4] = p;
        }
    }
    // ---- h1 weights/att (global, overlap with LDS drain) ----
    bf16x8 wf1[4][3];
    float asv[4][4], adv[4][4];
    #pragma unroll
    for (int cb = 0; cb < 4; cb++) {
        #pragma unroll
        for (int ks = 0; ks < 3; ks++)
            wf1[cb][ks] = *(const bf16x8*)(Wt1 + (size_t)(w * 64 + cb * 16 + lo) * 96 + ks * 32 + hi * 8);
        #pragma unroll
        for (int rg = 0; rg < 4; rg++) {
            asv[cb][rg] = as_[w * 64 + cb * 16 + hi * 4 + rg];
            adv[cb][rg] = ad_[w * 64 + cb * 16 + hi * 4 + rg];
        }
    }
    __syncthreads();
    // ---- h1 MFMA (wave w = head w, all 64 nodes) ----
    #pragma unroll
    for (int nb = 0; nb < 4; nb++) {
        f32x4 acc[4];
        #pragma unroll
        for (int cb = 0; cb < 4; cb++) acc[cb] = (f32x4){0.f, 0.f, 0.f, 0.f};
        #pragma unroll
        for (int ks = 0; ks < 3; ks++) {
            bf16x8 af = *(const bf16x8*)(&A1[nb * 16 + lo][ks * 32 + hi * 8]);
            #pragma unroll
            for (int cb = 0; cb < 4; cb++)
                acc[cb] = __builtin_amdgcn_mfma_f32_16x16x32_bf16(wf1[cb][ks], af, acc[cb], 0, 0, 0);
        }
        int nrow = n0 + nb * 16 + lo;
        float ps = 0.f, pd = 0.f;
        #pragma unroll
        for (int cb = 0; cb < 4; cb++) {
            uint2 p;
            p.x = pk2(acc[cb][0], acc[cb][1]);
            p.y = pk2(acc[cb][2], acc[cb][3]);
            *(uint2*)(h1 + (size_t)nrow * 256 + w * 64 + cb * 16 + hi * 4) = p;
            ps += acc[cb][0] * asv[cb][0] + acc[cb][1] * asv[cb][1]
                + acc[cb][2] * asv[cb][2] + acc[cb][3] * asv[cb][3];
            pd += acc[cb][0] * adv[cb][0] + acc[cb][1] * adv[cb][1]
                + acc[cb][2] * adv[cb][2] + acc[cb][3] * adv[cb][3];
        }
        ps += __shfl_xor(ps, 16, 64); ps += __shfl_xor(ps, 32, 64);
        pd += __shfl_xor(pd, 16, 64); pd += __shfl_xor(pd, 32, 64);
        if (hi == 0) {
            a1s[nrow * 4 + w] = ps;
            a1d[nrow * 4 + w] = pd;
        }
    }
}

// ---------- GAT1 fused softmax + gather (h1-space), depth-2 pipelined, min LDS ----------
__global__ __launch_bounds__(256) void k_sg1(const int* __restrict__ row_ptr, const int* __restrict__ ssrc,
                                             const float* __restrict__ a1s, const float* __restrict__ a1d,
                                             const float* __restrict__ a1es, const u16* __restrict__ h1,
                                             const float* __restrict__ bias, u16* __restrict__ out1) {
    __shared__ float wl[4][1024];   // per-wave: [edge<256][head<4]
    int t = threadIdx.x;
    int wv = t >> 6, L = t & 63;
    int n = blockIdx.x * 4 + wv;
    int beg = row_ptr[n], deg = row_ptr[n + 1] - beg;
    int lim = (deg < 256) ? deg : 256;
    {   // ---- phase 1 ----
        int h = L >> 4, j = L & 15;
        float adn = a1d[n * 4 + h];
        float m = -3.0e38f, s = 0.f;
        for (int i = j; i < deg; i += 16) {
            int pos = beg + i;
            float l = a1s[ssrc[pos] * 4 + h] + adn + a1es[(size_t)pos * 4 + h];
            l = (l > 0.f) ? l : 0.2f * l;
            if (i < 256) wl[wv][i * 4 + h] = l;
            if (l > m) { s = s * __expf(m - l) + 1.f; m = l; }
            else       { s += __expf(l - m); }
        }
        for (int o = 1; o < 16; o <<= 1) {
            float mo = __shfl_xor(m, o, 64), so = __shfl_xor(s, o, 64);
            float M = fmaxf(m, mo);
            s = s * __expf(m - M) + so * __expf(mo - M);
            m = M;
        }
        float inv = 1.f / (s + 1e-16f);
        for (int i = j; i < lim; i += 16)
            wl[wv][i * 4 + h] = __expf(wl[wv][i * 4 + h] - m) * inv;
    }
    // in-wave LDS handoff (waves independent)
    asm volatile("" ::: "memory");
    __builtin_amdgcn_s_waitcnt(0);
    // ---- phase 2: 2 banks x 4 slots = 8 gather loads in flight ----
    int halfE = L >> 5;
    int L32 = L & 31;
    int hd = L32 >> 3;
    float acc[8];
    #pragma unroll
    for (int j = 0; j < 8; j++) acc[j] = 0.f;
    uint4 U[8];
    float W[8];
    auto LD = [&](int k, int ii) {
        bool v = ii < deg;
        int iw = (ii < 255) ? ii : 255;
        int s = v ? ssrc[beg + ii] : 0;
        W[k] = v ? wl[wv][iw * 4 + hd] : 0.f;
        U[k] = *((const uint4*)(h1 + (size_t)s * 256) + L32);
    };
    #pragma unroll
    for (int k = 0; k < 8; k++) LD(k, 2 * (k & 3) + halfE + (k >> 2) * 8);
    for (int i = 0; i < deg; i += 16) {
        {   // consume bank A (edges i..i+7), prefetch A for i+16
            uint4 C0 = U[0], C1 = U[1], C2 = U[2], C3 = U[3];
            float W0 = W[0], W1 = W[1], W2 = W[2], W3 = W[3];
            #pragma unroll
            for (int k = 0; k < 4; k++) LD(k, i + 16 + 2 * k + halfE);
            acc[0] += W0 * lo16(C0.x) + W1 * lo16(C1.x) + W2 * lo16(C2.x) + W3 * lo16(C3.x);
            acc[1] += W0 * hi16(C0.x) + W1 * hi16(C1.x) + W2 * hi16(C2.x) + W3 * hi16(C3.x);
            acc[2] += W0 * lo16(C0.y) + W1 * lo16(C1.y) + W2 * lo16(C2.y) + W3 * lo16(C3.y);
            acc[3] += W0 * hi16(C0.y) + W1 * hi16(C1.y) + W2 * hi16(C2.y) + W3 * hi16(C3.y);
            acc[4] += W0 * lo16(C0.z) + W1 * lo16(C1.z) + W2 * lo16(C2.z) + W3 * lo16(C3.z);
            acc[5] += W0 * hi16(C0.z) + W1 * hi16(C1.z) + W2 * hi16(C2.z) + W3 * hi16(C3.z);
            acc[6] += W0 * lo16(C0.w) + W1 * lo16(C1.w) + W2 * lo16(C2.w) + W3 * lo16(C3.w);
            acc[7] += W0 * hi16(C0.w) + W1 * hi16(C1.w) + W2 * hi16(C2.w) + W3 * hi16(C3.w);
        }
        {   // consume bank B (edges i+8..i+15), prefetch B for i+24
            uint4 C0 = U[4], C1 = U[5], C2 = U[6], C3 = U[7];
            float W0 = W[4], W1 = W[5], W2 = W[6], W3 = W[7];
            #pragma unroll
            for (int k = 0; k < 4; k++) LD(4 + k, i + 24 + 2 * k + halfE);
            acc[0] += W0 * lo16(C0.x) + W1 * lo16(C1.x) + W2 * lo16(C2.x) + W3 * lo16(C3.x);
            acc[1] += W0 * hi16(C0.x) + W1 * hi16(C1.x) + W2 * hi16(C2.x) + W3 * hi16(C3.x);
            acc[2] += W0 * lo16(C0.y) + W1 * lo16(C1.y) + W2 * lo16(C2.y) + W3 * lo16(C3.y);
            acc[3] += W0 * hi16(C0.y) + W1 * hi16(C1.y) + W2 * hi16(C2.y) + W3 * hi16(C3.y);
            acc[4] += W0 * lo16(C0.z) + W1 * lo16(C1.z) + W2 * lo16(C2.z) + W3 * lo16(C3.z);
            acc[5] += W0 * hi16(C0.z) + W1 * hi16(C1.z) + W2 * hi16(C2.z) + W3 * hi16(C3.z);
            acc[6] += W0 * lo16(C0.w) + W1 * lo16(C1.w) + W2 * lo16(C2.w) + W3 * lo16(C3.w);
            acc[7] += W0 * hi16(C0.w) + W1 * hi16(C1.w) + W2 * hi16(C2.w) + W3 * hi16(C3.w);
        }
    }
    #pragma unroll
    for (int j = 0; j < 8; j++) acc[j] += __shfl_xor(acc[j], 32, 64);
    if (halfE == 0) {
        float4 b0 = *(const float4*)(bias + 8 * L32);
        float4 b1 = *(const float4*)(bias + 8 * L32 + 4);
        uint4 pk;
        pk.x = (u32)f2bf(fmaxf(acc[0] + b0.x, 0.f)) | ((u32)f2bf(fmaxf(acc[1] + b0.y, 0.f)) << 16);
        pk.y = (u32)f2bf(fmaxf(acc[2] + b0.z, 0.f)) | ((u32)f2bf(fmaxf(acc[3] + b0.w, 0.f)) << 16);
        pk.z = (u32)f2bf(fmaxf(acc[4] + b1.x, 0.f)) | ((u32)f2bf(fmaxf(acc[5] + b1.y, 0.f)) << 16);
        pk.w = (u32)f2bf(fmaxf(acc[6] + b1.z, 0.f)) | ((u32)f2bf(fmaxf(acc[7] + b1.w, 0.f)) << 16);
        *((uint4*)(out1 + (size_t)n * 256) + L32) = pk;
    }
}

// ---------- h2 = out1(bf16) @ g2Wt via MFMA, no LDS, fused a2s/a2d ----------
__global__ __launch_bounds__(256) void k_h2(const u16* __restrict__ A, const u16* __restrict__ Wt,
                                            const float* __restrict__ as_, const float* __restrict__ ad_,
                                            u16* __restrict__ out, float* __restrict__ a2s,
                                            float* __restrict__ a2d) {
    int t = threadIdx.x;
    int w = t >> 6, l = t & 63, lo = l & 15, hi = l >> 4;
    int nrow = blockIdx.x * 64 + w * 16 + lo;
    f32x4 acc[4];
    #pragma unroll
    for (int cb = 0; cb < 4; cb++) acc[cb] = (f32x4){0.f, 0.f, 0.f, 0.f};
    const u16* ap = A + (size_t)nrow * 256 + hi * 8;
    #pragma unroll
    for (int ks = 0; ks < 8; ks++) {
        bf16x8 af = *(const bf16x8*)(ap + ks * 32);
        #pragma unroll
        for (int cb = 0; cb < 4; cb++) {
            bf16x8 wf = *(const bf16x8*)(Wt + (size_t)(cb * 16 + lo) * 256 + ks * 32 + hi * 8);
            acc[cb] = __builtin_amdgcn_mfma_f32_16x16x32_bf16(wf, af, acc[cb], 0, 0, 0);
        }
    }
    float ps = 0.f, pd = 0.f;
    #pragma unroll
    for (int cb = 0; cb < 4; cb++) {
        uint2 p;
        p.x = pk2(acc[cb][0], acc[cb][1]);
        p.y = pk2(acc[cb][2], acc[cb][3]);
        *(uint2*)(out + (size_t)nrow * 64 + cb * 16 + hi * 4) = p;
        #pragma unroll
        for (int rg = 0; rg < 4; rg++) {
            float a = acc[cb][rg];
            ps += a * as_[cb * 16 + hi * 4 + rg];
            pd += a * ad_[cb * 16 + hi * 4 + rg];
        }
    }
    ps += __shfl_xor(ps, 16, 64); ps += __shfl_xor(ps, 32, 64);
    pd += __shfl_xor(pd, 16, 64); pd += __shfl_xor(pd, 32, 64);
    if (hi == 0) {
        a2s[nrow] = ps;
        a2d[nrow] = pd;
    }
}

// ---------- GAT2 fused softmax+gather, depth-2 pipelined, min LDS ----------
__global__ __launch_bounds__(256) void k_sg2(const int* __restrict__ row_ptr, const int* __restrict__ ssrc,
                                             const float* __restrict__ a2s, const float* __restrict__ a2d,
                                             const float* __restrict__ a2es, const u16* __restrict__ h2b,
                                             const float* __restrict__ bias, float* __restrict__ hfin) {
    __shared__ float wl[4][256];
    int t = threadIdx.x;
    int wv = t >> 6, L = t & 63;
    int n = blockIdx.x * 4 + wv;
    int beg = row_ptr[n], deg = row_ptr[n + 1] - beg;
    int lim = (deg < 256) ? deg : 256;
    {   // ---- phase 1 ----
        float adn = a2d[n];
        float m = -3.0e38f, s = 0.f;
        for (int i = L; i < deg; i += 64) {
            int pos = beg + i;
            float l = a2s[ssrc[pos]] + adn + a2es[pos];
            l = (l > 0.f) ? l : 0.2f * l;
            if (i < 256) wl[wv][i] = l;
            if (l > m) { s = s * __expf(m - l) + 1.f; m = l; }
            else       { s += __expf(l - m); }
        }
        for (int o = 1; o < 64; o <<= 1) {
            float mo = __shfl_xor(m, o, 64), so = __shfl_xor(s, o, 64);
            float M = fmaxf(m, mo);
            s = s * __expf(m - M) + so * __expf(mo - M);
            m = M;
        }
        float inv = 1.f / (s + 1e-16f);
        for (int i = L; i < lim; i += 64)
            wl[wv][i] = __expf(wl[wv][i] - m) * inv;
    }
    asm volatile("" ::: "memory");
    __builtin_amdgcn_s_waitcnt(0);
    // ---- phase 2: depth-2 pipelined ----
    int halfE = L >> 5;
    int L32 = L & 31;
    float a0 = 0.f, a1v = 0.f;
    const u32* h2u = (const u32*)h2b;
    u32 U[8];
    float W[8];
    auto LD = [&](int k, int ii) {
        bool v = ii < deg;
        int iw = (ii < 255) ? ii : 255;
        int s = v ? ssrc[beg + ii] : 0;
        W[k] = v ? wl[wv][iw] : 0.f;
        U[k] = h2u[(size_t)s * 32 + L32];
    };
    #pragma unroll
    for (int k = 0; k < 8; k++) LD(k, 2 * (k & 3) + halfE + (k >> 2) * 8);
    for (int i = 0; i < deg; i += 16) {
        {
            u32 C0 = U[0], C1 = U[1], C2 = U[2], C3 = U[3];
            float W0 = W[0], W1 = W[1], W2 = W[2], W3 = W[3];
            #pragma unroll
            for (int k = 0; k < 4; k++) LD(k, i + 16 + 2 * k + halfE);
            a0  += W0 * lo16(C0) + W1 * lo16(C1) + W2 * lo16(C2) + W3 * lo16(C3);
            a1v += W0 * hi16(C0) + W1 * hi16(C1) + W2 * hi16(C2) + W3 * hi16(C3);
        }
        {
            u32 C0 = U[4], C1 = U[5], C2 = U[6], C3 = U[7];
            float W0 = W[4], W1 = W[5], W2 = W[6], W3 = W[7];
            #pragma unroll
            for (int k = 0; k < 4; k++) LD(4 + k, i + 24 + 2 * k + halfE);
            a0  += W0 * lo16(C0) + W1 * lo16(C1) + W2 * lo16(C2) + W3 * lo16(C3);
            a1v += W0 * hi16(C0) + W1 * hi16(C1) + W2 * hi16(C2) + W3 * hi16(C3);
        }
    }
    a0  += __shfl_xor(a0, 32, 64);
    a1v += __shfl_xor(a1v, 32, 64);
    if (halfE == 0) {
        float2 o;
        o.x = a0  + bias[2 * L32];
        o.y = a1v + bias[2 * L32 + 1];
        *(float2*)(hfin + (size_t)n * 64 + 2 * L32) = o;
    }
}

// ---------- pooling + classifier ----------
__global__ __launch_bounds__(64) void k_pool(const int* __restrict__ bvec, const float* __restrict__ hf,
                                             const float* gateW, const float* gateb,
                                             const float* __restrict__ scene,
                                             const float* c1W, const float* c1b,
                                             const float* c2W, const float* c2b,
                                             float* __restrict__ outp) {
    int b = blockIdx.x, lane = threadIdx.x;
    __shared__ float gwl[64], se[64], comb[192], hid[64];
    gwl[lane] = gateW[lane];
    __syncthreads();
    int s0, s1;
    { int lo = 0, hi = N_NODES; while (lo < hi) { int mid = (lo + hi) >> 1; if (bvec[mid] < b) lo = mid + 1; else hi = mid; } s0 = lo; }
    { int lo = 0, hi = N_NODES; while (lo < hi) { int mid = (lo + hi) >> 1; if (bvec[mid] < b + 1) lo = mid + 1; else hi = mid; } s1 = lo; }
    float gb = gateb[0];
    float m = -3.0e38f, ssum = 0.f, acc = 0.f;
    for (int cs = s0; cs < s1; cs += 64) {
        int cnt = min(64, s1 - cs);
        float l = -3.0e38f;
        if (lane < cnt) {
            int n = cs + lane;
            float d = 0.f;
            for (int i = 0; i < 64; i++) d += hf[(size_t)n * 64 + i] * gwl[i];
            l = d + gb;
        }
        float cm = wmax(l);
        float newm = fmaxf(m, cm);
        float rsc = __expf(m - newm);
        float e = (lane < cnt) ? __expf(l - newm) : 0.f;
        float es = wsum(e);
        ssum = ssum * rsc + es;
        se[lane] = e;
        __syncthreads();
        float a2 = 0.f;
        for (int i = 0; i < cnt; i++) a2 += se[i] * hf[(size_t)(cs + i) * 64 + lane];
        acc = acc * rsc + a2;
        __syncthreads();
        m = newm;
    }
    float rel = acc / (ssum + 1e-16f);
    comb[lane] = scene[b * 128 + lane];
    comb[64 + lane] = scene[b * 128 + 64 + lane];
    comb[128 + lane] = rel;
    __syncthreads();
    float hj = 0.f;
    for (int k = 0; k < 192; k++) hj += comb[k] * c1W[k * 64 + lane];
    hj += c1b[lane];
    hid[lane] = fmaxf(hj, 0.f);
    __syncthreads();
    if (lane < 3) {
        float o = 0.f;
        for (int k = 0; k < 64; k++) o += hid[k] * c2W[k * 3 + lane];
        o += c2b[lane];
        outp[b * 3 + lane] = o;
    }
}

extern "C" void kernel_launch(void* const* d_in, const int* in_sizes, int n_in,
                              void* d_out, int out_size, void* d_ws, size_t ws_size,
                              hipStream_t stream) {
    (void)in_sizes; (void)n_in; (void)out_size; (void)ws_size;
    const float* gf     = (const float*)d_in[0];
    const float* x      = (const float*)d_in[1];
    const float* roi    = (const float*)d_in[2];
    const int*   ei     = (const int*)d_in[3];
    const float* ea     = (const float*)d_in[4];
    const int*   bvec   = (const int*)d_in[5];
    const float* roiW   = (const float*)d_in[6];
    const float* roib   = (const float*)d_in[7];
    const float* sceneW = (const float*)d_in[8];
    const float* sceneb = (const float*)d_in[9];
    const float* g1W    = (const float*)d_in[10];
    const float* g1as   = (const float*)d_in[11];
    const float* g1ad   = (const float*)d_in[12];
    const float* g1We   = (const float*)d_in[13];
    const float* g1ae   = (const float*)d_in[14];
    const float* g1b    = (const float*)d_in[15];
    const float* g2W    = (const float*)d_in[16];
    const float* g2as   = (const float*)d_in[17];
    const float* g2ad   = (const float*)d_in[18];
    const float* g2We   = (const float*)d_in[19];
    const float* g2ae   = (const float*)d_in[20];
    const float* g2b    = (const float*)d_in[21];
    const float* gateW  = (const float*)d_in[22];
    const float* gateb  = (const float*)d_in[23];
    const float* c1W    = (const float*)d_in[24];
    const float* c1b    = (const float*)d_in[25];
    const float* c2W    = (const float*)d_in[26];
    const float* c2b    = (const float*)d_in[27];

    char* w = (char*)d_ws;
    size_t o = 0;
    auto nxt = [&](size_t bytes) -> char* {
        char* p = w + o;
        o += (bytes + 255) & ~(size_t)255;
        return p;
    };
    float* scene  = (float*)nxt((size_t)NB * 128 * 4);
    float* M1     = (float*)nxt(80);
    float* M2     = (float*)nxt(32);
    u16* g1Wt     = (u16*)nxt((size_t)256 * 96 * 2);
    u16* roiWt    = (u16*)nxt((size_t)64 * 256 * 2);
    u16* g2Wt     = (u16*)nxt((size_t)64 * 256 * 2);
    int* cnt      = (int*)nxt((size_t)N_NODES * 4);
    int* pre      = (int*)nxt((size_t)N_NODES * 4);
    int* bsum     = (int*)nxt(64 * 4);
    int* row_ptr  = (int*)nxt((size_t)(N_NODES + 1) * 4);
    int* coarse   = (int*)nxt(256 * 4);
    u32* bpack    = (u32*)nxt((size_t)N_EDGES * 4);
    int* bsrc     = (int*)nxt((size_t)N_EDGES * 4);
    int* ssrc     = (int*)nxt((size_t)N_EDGES * 4);
    float* a1es   = (float*)nxt((size_t)N_EDGES * 16);
    float* a2es   = (float*)nxt((size_t)N_EDGES * 4);
    u16* h1       = (u16*)nxt((size_t)N_NODES * 256 * 2);
    u16* out1     = (u16*)nxt((size_t)N_NODES * 256 * 2);
    u16* h2b      = (u16*)nxt((size_t)N_NODES * 64 * 2);
    float* hfin   = (float*)nxt((size_t)N_NODES * 64 * 4);
    float* a1s    = (float*)nxt((size_t)N_NODES * 16);
    float* a1d    = (float*)nxt((size_t)N_NODES * 16);
    float* a2s    = (float*)nxt((size_t)N_NODES * 4);
    float* a2d    = (float*)nxt((size_t)N_NODES * 4);

    hipMemsetAsync(cnt, 0, (size_t)N_NODES * 4, stream);
    k_wprep<<<113, 512, 0, stream>>>(g1W, roiW, g2W, g1We, g1ae, g2We, g2ae,
                                     g1Wt, roiWt, g2Wt, M1, M2);
    k_scene<<<(NB * 128) / 256, 256, 0, stream>>>(gf, sceneW, sceneb, scene);
    k_hist<<<N_EDGES / 256, 256, 0, stream>>>(ei, cnt);
    k_scan_blk<<<64, 256, 0, stream>>>(cnt, pre, bsum);
    k_scan_top<<<1, 64, 0, stream>>>(bsum);
    k_scan_fix<<<N_NODES / 256, 256, 0, stream>>>(pre, bsum, row_ptr, coarse);
    k_bucket<<<256, 256, 0, stream>>>(ei, coarse, bpack, bsrc);
    k_sortp<<<256, 256, 0, stream>>>(bpack, bsrc, row_ptr, ea, M1, M2, ssrc, a1es, a2es);
    k_vh<<<N_NODES / 64, 256, 0, stream>>>(roi, roiWt, roib, x, g1Wt, g1as, g1ad, h1, a1s, a1d);
    k_sg1<<<N_NODES / 4, 256, 0, stream>>>(row_ptr, ssrc, a1s, a1d, a1es, h1, g1b, out1);
    k_h2<<<N_NODES / 64, 256, 0, stream>>>(out1, g2Wt, g2as, g2ad, h2b, a2s, a2d);
    k_sg2<<<N_NODES / 4, 256, 0, stream>>>(row_ptr, ssrc, a2s, a2d, a2es, h2b, g2b, hfin);
    k_pool<<<NB, 64, 0, stream>>>(bvec, hfin, gateW, gateb, scene, c1W, c1b, c2W, c2b, (float*)d_out);
}

// Round 7
// 534.878 us; speedup vs baseline: 1.1257x; 1.1257x over previous
//
#include <hip/hip_runtime.h>

#define N_NODES 65536
#define N_EDGES 1048576
#define NB      512

typedef unsigned short u16;
typedef unsigned int   u32;
typedef unsigned long long u64;

typedef __attribute__((ext_vector_type(8))) short bf16x8;
typedef __attribute__((ext_vector_type(4))) float f32x4;

__device__ __forceinline__ float bf2f(u16 u) { return __uint_as_float(((u32)u) << 16); }
__device__ __forceinline__ float lo16(u32 u) { return __uint_as_float(u << 16); }
__device__ __forceinline__ float hi16(u32 u) { return __uint_as_float(u & 0xffff0000u); }
__device__ __forceinline__ u16 f2bf(float f) {
    u32 u = __float_as_uint(f);
    u32 r = (u + 0x7fffu + ((u >> 16) & 1u)) >> 16;
    return (u16)r;
}
__device__ __forceinline__ u32 pk2(float a, float b) {
    return (u32)f2bf(a) | ((u32)f2bf(b) << 16);
}
__device__ __forceinline__ float wsum(float v) {
    for (int o = 32; o; o >>= 1) v += __shfl_xor(v, o, 64);
    return v;
}
__device__ __forceinline__ float wmax(float v) {
    for (int o = 32; o; o >>= 1) v = fmaxf(v, __shfl_xor(v, o, 64));
    return v;
}

// ---------- mega prep: all weight transposes + M1/M2 in one launch ----------
__global__ __launch_bounds__(512) void k_wprep(const float* __restrict__ g1W, const float* __restrict__ roiW,
                                               const float* __restrict__ g2W,
                                               const float* __restrict__ g1We, const float* __restrict__ g1ae,
                                               const float* __restrict__ g2We, const float* __restrict__ g2ae,
                                               u16* __restrict__ g1Wt, u16* __restrict__ roiWt,
                                               u16* __restrict__ g2Wt, float* __restrict__ M1,
                                               float* __restrict__ M2) {
    int b = blockIdx.x, t = threadIdx.x;
    if (b < 48) {
        int idx = b * 512 + t;          // 0..24575 = 256*96
        int c = idx / 96, k = idx - 96 * c;
        float v = 0.f;
        if (k < 77) {
            int ko = (k < 64) ? (13 + k) : (k - 64);
            v = g1W[(size_t)ko * 256 + c];
        }
        g1Wt[idx] = f2bf(v);
    } else if (b < 80) {
        int idx = (b - 48) * 512 + t;   // 0..16383 = 64*256
        int c = idx >> 8, k = idx & 255;
        roiWt[idx] = f2bf(roiW[(size_t)k * 64 + c]);
    } else if (b < 112) {
        int idx = (b - 80) * 512 + t;
        int c = idx >> 8, k = idx & 255;
        g2Wt[idx] = f2bf(g2W[(size_t)k * 64 + c]);
    } else {
        if (t < 20) {
            int j = t >> 2, h = t & 3;
            float s = 0.f;
            for (int c = 0; c < 64; c++) s += g1We[j * 256 + h * 64 + c] * g1ae[h * 64 + c];
            M1[t] = s;
        } else if (t < 25) {
            int j = t - 20;
            float s = 0.f;
            for (int c = 0; c < 64; c++) s += g2We[j * 64 + c] * g2ae[c];
            M2[j] = s;
        }
    }
}

// ---------- scene ----------
__global__ __launch_bounds__(256) void k_scene(const float* __restrict__ gf, const float* __restrict__ W,
                                               const float* __restrict__ bias, float* __restrict__ scene) {
    int idx = blockIdx.x * 256 + threadIdx.x;
    int b = idx >> 7, j = idx & 127;
    float acc = 0.f;
    for (int k = 0; k < 512; k++) acc += gf[b * 512 + k] * W[k * 128 + j];
    scene[idx] = acc + bias[j];
}

// ---------- histogram ----------
__global__ __launch_bounds__(256) void k_hist(const int* ei, int* cnt) {
    int e = blockIdx.x * 256 + threadIdx.x;
    atomicAdd(&cnt[ei[N_EDGES + e]], 1);
}

// ---------- hierarchical exclusive scan ----------
__global__ __launch_bounds__(256) void k_scan_blk(const int* __restrict__ cnt, int* __restrict__ pre,
                                                  int* __restrict__ bsum) {
    __shared__ int sd[256];
    int t = threadIdx.x, b = blockIdx.x;
    int base = b * 1024 + t * 4;
    int4 c = *(const int4*)(cnt + base);
    int s = c.x + c.y + c.z + c.w;
    sd[t] = s;
    __syncthreads();
    for (int off = 1; off < 256; off <<= 1) {
        int v = (t >= off) ? sd[t - off] : 0;
        __syncthreads();
        sd[t] += v;
        __syncthreads();
    }
    int excl = sd[t] - s;
    int4 p;
    p.x = excl;
    p.y = excl + c.x;
    p.z = excl + c.x + c.y;
    p.w = excl + c.x + c.y + c.z;
    *(int4*)(pre + base) = p;
    if (t == 255) bsum[b] = sd[255];
}

__global__ __launch_bounds__(64) void k_scan_top(int* bsum) {
    int t = threadIdx.x;
    int v = bsum[t];
    int inc = v;
    for (int off = 1; off < 64; off <<= 1) {
        int u = __shfl_up(inc, off, 64);
        if (t >= off) inc += u;
    }
    bsum[t] = inc - v;
}

__global__ __launch_bounds__(256) void k_scan_fix(const int* __restrict__ pre, const int* __restrict__ bsum,
                                                  int* __restrict__ row_ptr, int* __restrict__ coarse_cur) {
    int i = blockIdx.x * 256 + threadIdx.x;
    int v = pre[i] + bsum[i >> 10];
    row_ptr[i] = v;
    if ((i & 255) == 0) coarse_cur[i >> 8] = v;
    if (i == 0) row_ptr[N_NODES] = N_EDGES;
}

// ---------- bucket pass (R2-proven shape: 256 blocks x 4096 edges) ----------
__global__ __launch_bounds__(256) void k_bucket(const int* __restrict__ ei, int* coarse_cur,
                                                u32* __restrict__ bpack, int* __restrict__ bsrc) {
    __shared__ u32 stageP[4096];
    __shared__ int stageS[4096];
    __shared__ int bcnt[256], bscan[256], boff[256], gbase[256];
    int t = threadIdx.x;
    int e0 = blockIdx.x * 4096;
    bcnt[t] = 0;
    __syncthreads();
    int dreg[16], sreg[16];
    for (int it = 0; it < 16; it++) {
        int e = e0 + it * 256 + t;
        int dd = ei[N_EDGES + e];
        dreg[it] = dd;
        sreg[it] = ei[e];
        atomicAdd(&bcnt[dd >> 8], 1);
    }
    __syncthreads();
    int v = bcnt[t];
    bscan[t] = v;
    __syncthreads();
    for (int off = 1; off < 256; off <<= 1) {
        int u = (t >= off) ? bscan[t - off] : 0;
        __syncthreads();
        bscan[t] += u;
        __syncthreads();
    }
    boff[t] = bscan[t] - v;
    gbase[t] = v ? atomicAdd(&coarse_cur[t], v) : 0;
    __syncthreads();
    for (int it = 0; it < 16; it++) {
        int e = e0 + it * 256 + t;
        int b = dreg[it] >> 8;
        int pos = atomicAdd(&boff[b], 1);
        stageP[pos] = ((u32)e << 12) | (u32)(dreg[it] & 255);
        stageS[pos] = sreg[it];
    }
    __syncthreads();
    for (int idx = t; idx < 4096; idx += 256) {
        int lo = 0, hi = 255;
        while (lo < hi) { int mid = (lo + hi) >> 1; if (bscan[mid] > idx) hi = mid; else lo = mid + 1; }
        int b = lo;
        int g = gbase[b] + (idx - (bscan[b] - bcnt[b]));
        bpack[g] = stageP[idx];
        bsrc[g] = stageS[idx];
    }
}

// ---------- local sort within bucket, fused with payload ----------
__global__ __launch_bounds__(256) void k_sortp(const u32* __restrict__ bpack, const int* __restrict__ bsrc,
                                               const int* __restrict__ row_ptr, const float* __restrict__ ea,
                                               const float* __restrict__ M1, const float* __restrict__ M2,
                                               int* __restrict__ ssrc, float* __restrict__ a1es,
                                               float* __restrict__ a2es) {
    __shared__ int cur[256];
    int t = threadIdx.x, b = blockIdx.x;
    int nbase = b * 256;
    cur[t] = row_ptr[nbase + t];
    __syncthreads();
    float m1[20], m2[5];
    #pragma unroll
    for (int j = 0; j < 20; j++) m1[j] = M1[j];
    #pragma unroll
    for (int j = 0; j < 5; j++) m2[j] = M2[j];
    int beg = row_ptr[nbase];
    int end = row_ptr[nbase + 256];
    for (int i = beg + t; i < end; i += 256) {
        u32 wd = bpack[i];
        int src = bsrc[i];
        int d8 = wd & 255;
        int e = (int)(wd >> 12);
        int pos = atomicAdd(&cur[d8], 1);
        ssrc[pos] = src;
        const float* ep = ea + (size_t)e * 5;
        float v0 = ep[0], v1 = ep[1], v2 = ep[2], v3 = ep[3], v4 = ep[4];
        float4 o;
        o.x = v0*m1[0]  + v1*m1[4]  + v2*m1[8]  + v3*m1[12] + v4*m1[16];
        o.y = v0*m1[1]  + v1*m1[5]  + v2*m1[9]  + v3*m1[13] + v4*m1[17];
        o.z = v0*m1[2]  + v1*m1[6]  + v2*m1[10] + v3*m1[14] + v4*m1[18];
        o.w = v0*m1[3]  + v1*m1[7]  + v2*m1[11] + v3*m1[15] + v4*m1[19];
        *(float4*)(a1es + (size_t)pos * 4) = o;
        a2es[pos] = v0*m2[0] + v1*m2[1] + v2*m2[2] + v3*m2[3] + v4*m2[4];
    }
}

// ---------- fused vis+h1: vis = relu(roi@roiW+b) -> LDS only; h1 = [vis|x]@g1Wt + a1s/a1d ----------
__global__ __launch_bounds__(256) void k_vh(const float* __restrict__ roi, const u16* __restrict__ WtV,
                                            const float* __restrict__ visb, const float* __restrict__ x,
                                            const u16* __restrict__ Wt1,
                                            const float* __restrict__ as_, const float* __restrict__ ad_,
                                            u16* __restrict__ h1, float* __restrict__ a1s,
                                            float* __restrict__ a1d) {
    __shared__ u16 At[64][264];   // roi staged bf16 (K=256)
    __shared__ u16 A1[64][104];   // [vis(64) | x(13) | 0..] staged bf16 (K'=96)
    int t = threadIdx.x;
    int w = t >> 6, l = t & 63, lo = l & 15, hi = l >> 4;
    int n0 = blockIdx.x * 64;
    int r = t >> 2, sub = t & 3;
    // stage roi -> At
    const float* rp = roi + (size_t)(n0 + r) * 256 + sub * 4;
    #pragma unroll
    for (int q = 0; q < 16; q++) {
        float4 v = *(const float4*)(rp + q * 16);
        uint2 p;
        p.x = pk2(v.x, v.y);
        p.y = pk2(v.z, v.w);
        *(uint2*)&At[r][q * 16 + sub * 4] = p;
    }
    // x part + zero pad into A1 (independent of vis)
    if (sub == 0) {
        const float* xp = x + (size_t)(n0 + r) * 13;
        #pragma unroll
        for (int j = 0; j < 13; j++) A1[r][64 + j] = f2bf(xp[j]);
    } else if (sub == 1) {
        #pragma unroll
        for (int j = 77; j < 96; j++) A1[r][j] = 0;
    }
    float bb[4][4];
    #pragma unroll
    for (int cb = 0; cb < 4; cb++)
        #pragma unroll
        for (int rg = 0; rg < 4; rg++) bb[cb][rg] = visb[cb * 16 + hi * 4 + rg];
    __syncthreads();
    // ---- vis MFMA (wave w: nodes w*16+lo, all 64 ch) ----
    {
        f32x4 acc[4];
        #pragma unroll
        for (int cb = 0; cb < 4; cb++) acc[cb] = (f32x4){0.f, 0.f, 0.f, 0.f};
        #pragma unroll
        for (int ks = 0; ks < 8; ks++) {
            bf16x8 af = *(const bf16x8*)(&At[w * 16 + lo][ks * 32 + hi * 8]);
            #pragma unroll
            for (int cb = 0; cb < 4; cb++) {
                bf16x8 wf = *(const bf16x8*)(WtV + (size_t)(cb * 16 + lo) * 256 + ks * 32 + hi * 8);
                acc[cb] = __builtin_amdgcn_mfma_f32_16x16x32_bf16(wf, af, acc[cb], 0, 0, 0);
            }
        }
        #pragma unroll
        for (int cb = 0; cb < 4; cb++) {
            uint2 p;
            p.x = pk2(fmaxf(acc[cb][0] + bb[cb][0], 0.f), fmaxf(acc[cb][1] + bb[cb][1], 0.f));
            p.y = pk2(fmaxf(acc[cb][2] + bb[cb][2], 0.f), fmaxf(acc[cb][3] + bb[cb][3], 0.f));
            *(uint2*)&A1[w * 16 + lo][cb * 16 + hi * 4] = p;
        }
    }
    // ---- h1 weights/att (global, overlap with LDS drain) ----
    bf16x8 wf1[4][3];
    float asv[4][4], adv[4][4];
    #pragma unroll
    for (int cb = 0; cb < 4; cb++) {
        #pragma unroll
        for (int ks = 0; ks < 3; ks++)
            wf1[cb][ks] = *(const bf16x8*)(Wt1 + (size_t)(w * 64 + cb * 16 + lo) * 96 + ks * 32 + hi * 8);
        #pragma unroll
        for (int rg = 0; rg < 4; rg++) {
            asv[cb][rg] = as_[w * 64 + cb * 16 + hi * 4 + rg];
            adv[cb][rg] = ad_[w * 64 + cb * 16 + hi * 4 + rg];
        }
    }
    __syncthreads();
    // ---- h1 MFMA (wave w = head w, all 64 nodes) ----
    #pragma unroll
    for (int nb = 0; nb < 4; nb++) {
        f32x4 acc[4];
        #pragma unroll
        for (int cb = 0; cb < 4; cb++) acc[cb] = (f32x4){0.f, 0.f, 0.f, 0.f};
        #pragma unroll
        for (int ks = 0; ks < 3; ks++) {
            bf16x8 af = *(const bf16x8*)(&A1[nb * 16 + lo][ks * 32 + hi * 8]);
            #pragma unroll
            for (int cb = 0; cb < 4; cb++)
                acc[cb] = __builtin_amdgcn_mfma_f32_16x16x32_bf16(wf1[cb][ks], af, acc[cb], 0, 0, 0);
        }
        int nrow = n0 + nb * 16 + lo;
        float ps = 0.f, pd = 0.f;
        #pragma unroll
        for (int cb = 0; cb < 4; cb++) {
            uint2 p;
            p.x = pk2(acc[cb][0], acc[cb][1]);
            p.y = pk2(acc[cb][2], acc[cb][3]);
            *(uint2*)(h1 + (size_t)nrow * 256 + w * 64 + cb * 16 + hi * 4) = p;
            ps += acc[cb][0] * asv[cb][0] + acc[cb][1] * asv[cb][1]
                + acc[cb][2] * asv[cb][2] + acc[cb][3] * asv[cb][3];
            pd += acc[cb][0] * adv[cb][0] + acc[cb][1] * adv[cb][1]
                + acc[cb][2] * adv[cb][2] + acc[cb][3] * adv[cb][3];
        }
        ps += __shfl_xor(ps, 16, 64); ps += __shfl_xor(ps, 32, 64);
        pd += __shfl_xor(pd, 16, 64); pd += __shfl_xor(pd, 32, 64);
        if (hi == 0) {
            a1s[nrow * 4 + w] = ps;
            a1d[nrow * 4 + w] = pd;
        }
    }
}

// ---------- GAT1 fused softmax+gather: EXACT R2 form (VGPR 36 / 67% occ proven) ----------
__global__ __launch_bounds__(256) void k_sg1(const int* __restrict__ row_ptr, const int* __restrict__ ssrc,
                                             const float* __restrict__ a1s, const float* __restrict__ a1d,
                                             const float* __restrict__ a1es, const u16* __restrict__ h1,
                                             const float* __restrict__ bias, u16* __restrict__ out1) {
    __shared__ float wl[4][1024];   // per-wave: [edge<256][head<4]
    int t = threadIdx.x;
    int wv = t >> 6, L = t & 63;
    int n = blockIdx.x * 4 + wv;
    int beg = row_ptr[n], deg = row_ptr[n + 1] - beg;
    int lim = (deg < 256) ? deg : 256;
    {   // ---- phase 1 ----
        int h = L >> 4, j = L & 15;
        float adn = a1d[n * 4 + h];
        float m = -3.0e38f, s = 0.f;
        for (int i = j; i < deg; i += 16) {
            int pos = beg + i;
            float l = a1s[ssrc[pos] * 4 + h] + adn + a1es[(size_t)pos * 4 + h];
            l = (l > 0.f) ? l : 0.2f * l;
            if (i < 256) wl[wv][i * 4 + h] = l;
            if (l > m) { s = s * __expf(m - l) + 1.f; m = l; }
            else       { s += __expf(l - m); }
        }
        for (int o = 1; o < 16; o <<= 1) {
            float mo = __shfl_xor(m, o, 64), so = __shfl_xor(s, o, 64);
            float M = fmaxf(m, mo);
            s = s * __expf(m - M) + so * __expf(mo - M);
            m = M;
        }
        float inv = 1.f / (s + 1e-16f);
        for (int i = j; i < lim; i += 16)
            wl[wv][i * 4 + h] = __expf(wl[wv][i * 4 + h] - m) * inv;
    }
    __syncthreads();
    // ---- phase 2 ----
    int halfE = L >> 5;
    int L32 = L & 31;
    int hd = L32 >> 3;
    float acc[8];
    #pragma unroll
    for (int j = 0; j < 8; j++) acc[j] = 0.f;
    int last = beg + deg - 1;
    for (int i = 0; i < deg; i += 8) {
        int iA = i + halfE, iB = i + 2 + halfE, iC = i + 4 + halfE, iD = i + 6 + halfE;
        bool vA = iA < deg, vB = iB < deg, vC = iC < deg, vD = iD < deg;
        int cA = vA ? beg + iA : last, cB = vB ? beg + iB : last;
        int cC = vC ? beg + iC : last, cD = vD ? beg + iD : last;
        int sA = ssrc[cA], sB = ssrc[cB], sC = ssrc[cC], sD = ssrc[cD];
        float wA = vA ? wl[wv][iA * 4 + hd] : 0.f;
        float wB = vB ? wl[wv][iB * 4 + hd] : 0.f;
        float wC = vC ? wl[wv][iC * 4 + hd] : 0.f;
        float wD = vD ? wl[wv][iD * 4 + hd] : 0.f;
        uint4 uA = *((const uint4*)(h1 + (size_t)sA * 256) + L32);
        uint4 uB = *((const uint4*)(h1 + (size_t)sB * 256) + L32);
        uint4 uC = *((const uint4*)(h1 + (size_t)sC * 256) + L32);
        uint4 uD = *((const uint4*)(h1 + (size_t)sD * 256) + L32);
        acc[0] += wA * lo16(uA.x) + wB * lo16(uB.x) + wC * lo16(uC.x) + wD * lo16(uD.x);
        acc[1] += wA * hi16(uA.x) + wB * hi16(uB.x) + wC * hi16(uC.x) + wD * hi16(uD.x);
        acc[2] += wA * lo16(uA.y) + wB * lo16(uB.y) + wC * lo16(uC.y) + wD * lo16(uD.y);
        acc[3] += wA * hi16(uA.y) + wB * hi16(uB.y) + wC * hi16(uC.y) + wD * hi16(uD.y);
        acc[4] += wA * lo16(uA.z) + wB * lo16(uB.z) + wC * lo16(uC.z) + wD * lo16(uD.z);
        acc[5] += wA * hi16(uA.z) + wB * hi16(uB.z) + wC * hi16(uC.z) + wD * hi16(uD.z);
        acc[6] += wA * lo16(uA.w) + wB * lo16(uB.w) + wC * lo16(uC.w) + wD * lo16(uD.w);
        acc[7] += wA * hi16(uA.w) + wB * hi16(uB.w) + wC * hi16(uC.w) + wD * hi16(uD.w);
    }
    #pragma unroll
    for (int j = 0; j < 8; j++) acc[j] += __shfl_xor(acc[j], 32, 64);
    if (halfE == 0) {
        float4 b0 = *(const float4*)(bias + 8 * L32);
        float4 b1 = *(const float4*)(bias + 8 * L32 + 4);
        uint4 pk;
        pk.x = (u32)f2bf(fmaxf(acc[0] + b0.x, 0.f)) | ((u32)f2bf(fmaxf(acc[1] + b0.y, 0.f)) << 16);
        pk.y = (u32)f2bf(fmaxf(acc[2] + b0.z, 0.f)) | ((u32)f2bf(fmaxf(acc[3] + b0.w, 0.f)) << 16);
        pk.z = (u32)f2bf(fmaxf(acc[4] + b1.x, 0.f)) | ((u32)f2bf(fmaxf(acc[5] + b1.y, 0.f)) << 16);
        pk.w = (u32)f2bf(fmaxf(acc[6] + b1.z, 0.f)) | ((u32)f2bf(fmaxf(acc[7] + b1.w, 0.f)) << 16);
        *((uint4*)(out1 + (size_t)n * 256) + L32) = pk;
    }
}

// ---------- h2 = out1(bf16) @ g2Wt via MFMA, no LDS, fused a2s/a2d ----------
__global__ __launch_bounds__(256) void k_h2(const u16* __restrict__ A, const u16* __restrict__ Wt,
                                            const float* __restrict__ as_, const float* __restrict__ ad_,
                                            u16* __restrict__ out, float* __restrict__ a2s,
                                            float* __restrict__ a2d) {
    int t = threadIdx.x;
    int w = t >> 6, l = t & 63, lo = l & 15, hi = l >> 4;
    int nrow = blockIdx.x * 64 + w * 16 + lo;
    f32x4 acc[4];
    #pragma unroll
    for (int cb = 0; cb < 4; cb++) acc[cb] = (f32x4){0.f, 0.f, 0.f, 0.f};
    const u16* ap = A + (size_t)nrow * 256 + hi * 8;
    #pragma unroll
    for (int ks = 0; ks < 8; ks++) {
        bf16x8 af = *(const bf16x8*)(ap + ks * 32);
        #pragma unroll
        for (int cb = 0; cb < 4; cb++) {
            bf16x8 wf = *(const bf16x8*)(Wt + (size_t)(cb * 16 + lo) * 256 + ks * 32 + hi * 8);
            acc[cb] = __builtin_amdgcn_mfma_f32_16x16x32_bf16(wf, af, acc[cb], 0, 0, 0);
        }
    }
    float ps = 0.f, pd = 0.f;
    #pragma unroll
    for (int cb = 0; cb < 4; cb++) {
        uint2 p;
        p.x = pk2(acc[cb][0], acc[cb][1]);
        p.y = pk2(acc[cb][2], acc[cb][3]);
        *(uint2*)(out + (size_t)nrow * 64 + cb * 16 + hi * 4) = p;
        #pragma unroll
        for (int rg = 0; rg < 4; rg++) {
            float a = acc[cb][rg];
            ps += a * as_[cb * 16 + hi * 4 + rg];
            pd += a * ad_[cb * 16 + hi * 4 + rg];
        }
    }
    ps += __shfl_xor(ps, 16, 64); ps += __shfl_xor(ps, 32, 64);
    pd += __shfl_xor(pd, 16, 64); pd += __shfl_xor(pd, 32, 64);
    if (hi == 0) {
        a2s[nrow] = ps;
        a2d[nrow] = pd;
    }
}

// ---------- GAT2 fused softmax+gather: EXACT R2 form ----------
__global__ __launch_bounds__(256) void k_sg2(const int* __restrict__ row_ptr, const int* __restrict__ ssrc,
                                             const float* __restrict__ a2s, const float* __restrict__ a2d,
                                             const float* __restrict__ a2es, const u16* __restrict__ h2b,
                                             const float* __restrict__ bias, float* __restrict__ hfin) {
    __shared__ float wl[4][256];
    int t = threadIdx.x;
    int wv = t >> 6, L = t & 63;
    int n = blockIdx.x * 4 + wv;
    int beg = row_ptr[n], deg = row_ptr[n + 1] - beg;
    int lim = (deg < 256) ? deg : 256;
    {   // ---- phase 1 ----
        float adn = a2d[n];
        float m = -3.0e38f, s = 0.f;
        for (int i = L; i < deg; i += 64) {
            int pos = beg + i;
            float l = a2s[ssrc[pos]] + adn + a2es[pos];
            l = (l > 0.f) ? l : 0.2f * l;
            if (i < 256) wl[wv][i] = l;
            if (l > m) { s = s * __expf(m - l) + 1.f; m = l; }
            else       { s += __expf(l - m); }
        }
        for (int o = 1; o < 64; o <<= 1) {
            float mo = __shfl_xor(m, o, 64), so = __shfl_xor(s, o, 64);
            float M = fmaxf(m, mo);
            s = s * __expf(m - M) + so * __expf(mo - M);
            m = M;
        }
        float inv = 1.f / (s + 1e-16f);
        for (int i = L; i < lim; i += 64)
            wl[wv][i] = __expf(wl[wv][i] - m) * inv;
    }
    __syncthreads();
    // ---- phase 2 ----
    int halfE = L >> 5;
    int L32 = L & 31;
    float a0 = 0.f, a1v = 0.f;
    int last = beg + deg - 1;
    const u32* h2u = (const u32*)h2b;
    for (int i = 0; i < deg; i += 8) {
        int iA = i + halfE, iB = i + 2 + halfE, iC = i + 4 + halfE, iD = i + 6 + halfE;
        bool vA = iA < deg, vB = iB < deg, vC = iC < deg, vD = iD < deg;
        int cA = vA ? beg + iA : last, cB = vB ? beg + iB : last;
        int cC = vC ? beg + iC : last, cD = vD ? beg + iD : last;
        int sA = ssrc[cA], sB = ssrc[cB], sC = ssrc[cC], sD = ssrc[cD];
        float wA = vA ? wl[wv][iA] : 0.f;
        float wB = vB ? wl[wv][iB] : 0.f;
        float wC = vC ? wl[wv][iC] : 0.f;
        float wD = vD ? wl[wv][iD] : 0.f;
        u32 uA = h2u[(size_t)sA * 32 + L32];
        u32 uB = h2u[(size_t)sB * 32 + L32];
        u32 uC = h2u[(size_t)sC * 32 + L32];
        u32 uD = h2u[(size_t)sD * 32 + L32];
        a0  += wA * lo16(uA) + wB * lo16(uB) + wC * lo16(uC) + wD * lo16(uD);
        a1v += wA * hi16(uA) + wB * hi16(uB) + wC * hi16(uC) + wD * hi16(uD);
    }
    a0  += __shfl_xor(a0, 32, 64);
    a1v += __shfl_xor(a1v, 32, 64);
    if (halfE == 0) {
        float2 o;
        o.x = a0  + bias[2 * L32];
        o.y = a1v + bias[2 * L32 + 1];
        *(float2*)(hfin + (size_t)n * 64 + 2 * L32) = o;
    }
}

// ---------- pooling + classifier ----------
__global__ __launch_bounds__(64) void k_pool(const int* __restrict__ bvec, const float* __restrict__ hf,
                                             const float* gateW, const float* gateb,
                                             const float* __restrict__ scene,
                                             const float* c1W, const float* c1b,
                                             const float* c2W, const float* c2b,
                                             float* __restrict__ outp) {
    int b = blockIdx.x, lane = threadIdx.x;
    __shared__ float gwl[64], se[64], comb[192], hid[64];
    gwl[lane] = gateW[lane];
    __syncthreads();
    int s0, s1;
    { int lo = 0, hi = N_NODES; while (lo < hi) { int mid = (lo + hi) >> 1; if (bvec[mid] < b) lo = mid + 1; else hi = mid; } s0 = lo; }
    { int lo = 0, hi = N_NODES; while (lo < hi) { int mid = (lo + hi) >> 1; if (bvec[mid] < b + 1) lo = mid + 1; else hi = mid; } s1 = lo; }
    float gb = gateb[0];
    float m = -3.0e38f, ssum = 0.f, acc = 0.f;
    for (int cs = s0; cs < s1; cs += 64) {
        int cnt = min(64, s1 - cs);
        float l = -3.0e38f;
        if (lane < cnt) {
            int n = cs + lane;
            float d = 0.f;
            for (int i = 0; i < 64; i++) d += hf[(size_t)n * 64 + i] * gwl[i];
            l = d + gb;
        }
        float cm = wmax(l);
        float newm = fmaxf(m, cm);
        float rsc = __expf(m - newm);
        float e = (lane < cnt) ? __expf(l - newm) : 0.f;
        float es = wsum(e);
        ssum = ssum * rsc + es;
        se[lane] = e;
        __syncthreads();
        float a2 = 0.f;
        for (int i = 0; i < cnt; i++) a2 += se[i] * hf[(size_t)(cs + i) * 64 + lane];
        acc = acc * rsc + a2;
        __syncthreads();
        m = newm;
    }
    float rel = acc / (ssum + 1e-16f);
    comb[lane] = scene[b * 128 + lane];
    comb[64 + lane] = scene[b * 128 + 64 + lane];
    comb[128 + lane] = rel;
    __syncthreads();
    float hj = 0.f;
    for (int k = 0; k < 192; k++) hj += comb[k] * c1W[k * 64 + lane];
    hj += c1b[lane];
    hid[lane] = fmaxf(hj, 0.f);
    __syncthreads();
    if (lane < 3) {
        float o = 0.f;
        for (int k = 0; k < 64; k++) o += hid[k] * c2W[k * 3 + lane];
        o += c2b[lane];
        outp[b * 3 + lane] = o;
    }
}

extern "C" void kernel_launch(void* const* d_in, const int* in_sizes, int n_in,
                              void* d_out, int out_size, void* d_ws, size_t ws_size,
                              hipStream_t stream) {
    (void)in_sizes; (void)n_in; (void)out_size; (void)ws_size;
    const float* gf     = (const float*)d_in[0];
    const float* x      = (const float*)d_in[1];
    const float* roi    = (const float*)d_in[2];
    const int*   ei     = (const int*)d_in[3];
    const float* ea     = (const float*)d_in[4];
    const int*   bvec   = (const int*)d_in[5];
    const float* roiW   = (const float*)d_in[6];
    const float* roib   = (const float*)d_in[7];
    const float* sceneW = (const float*)d_in[8];
    const float* sceneb = (const float*)d_in[9];
    const float* g1W    = (const float*)d_in[10];
    const float* g1as   = (const float*)d_in[11];
    const float* g1ad   = (const float*)d_in[12];
    const float* g1We   = (const float*)d_in[13];
    const float* g1ae   = (const float*)d_in[14];
    const float* g1b    = (const float*)d_in[15];
    const float* g2W    = (const float*)d_in[16];
    const float* g2as   = (const float*)d_in[17];
    const float* g2ad   = (const float*)d_in[18];
    const float* g2We   = (const float*)d_in[19];
    const float* g2ae   = (const float*)d_in[20];
    const float* g2b    = (const float*)d_in[21];
    const float* gateW  = (const float*)d_in[22];
    const float* gateb  = (const float*)d_in[23];
    const float* c1W    = (const float*)d_in[24];
    const float* c1b    = (const float*)d_in[25];
    const float* c2W    = (const float*)d_in[26];
    const float* c2b    = (const float*)d_in[27];

    char* w = (char*)d_ws;
    size_t o = 0;
    auto nxt = [&](size_t bytes) -> char* {
        char* p = w + o;
        o += (bytes + 255) & ~(size_t)255;
        return p;
    };
    float* scene  = (float*)nxt((size_t)NB * 128 * 4);
    float* M1     = (float*)nxt(80);
    float* M2     = (float*)nxt(32);
    u16* g1Wt     = (u16*)nxt((size_t)256 * 96 * 2);
    u16* roiWt    = (u16*)nxt((size_t)64 * 256 * 2);
    u16* g2Wt     = (u16*)nxt((size_t)64 * 256 * 2);
    int* cnt      = (int*)nxt((size_t)N_NODES * 4);
    int* pre      = (int*)nxt((size_t)N_NODES * 4);
    int* bsum     = (int*)nxt(64 * 4);
    int* row_ptr  = (int*)nxt((size_t)(N_NODES + 1) * 4);
    int* coarse   = (int*)nxt(256 * 4);
    u32* bpack    = (u32*)nxt((size_t)N_EDGES * 4);
    int* bsrc     = (int*)nxt((size_t)N_EDGES * 4);
    int* ssrc     = (int*)nxt((size_t)N_EDGES * 4);
    float* a1es   = (float*)nxt((size_t)N_EDGES * 16);
    float* a2es   = (float*)nxt((size_t)N_EDGES * 4);
    u16* h1       = (u16*)nxt((size_t)N_NODES * 256 * 2);
    u16* out1     = (u16*)nxt((size_t)N_NODES * 256 * 2);
    u16* h2b      = (u16*)nxt((size_t)N_NODES * 64 * 2);
    float* hfin   = (float*)nxt((size_t)N_NODES * 64 * 4);
    float* a1s    = (float*)nxt((size_t)N_NODES * 16);
    float* a1d    = (float*)nxt((size_t)N_NODES * 16);
    float* a2s    = (float*)nxt((size_t)N_NODES * 4);
    float* a2d    = (float*)nxt((size_t)N_NODES * 4);

    hipMemsetAsync(cnt, 0, (size_t)N_NODES * 4, stream);
    k_wprep<<<113, 512, 0, stream>>>(g1W, roiW, g2W, g1We, g1ae, g2We, g2ae,
                                     g1Wt, roiWt, g2Wt, M1, M2);
    k_scene<<<(NB * 128) / 256, 256, 0, stream>>>(gf, sceneW, sceneb, scene);
    k_hist<<<N_EDGES / 256, 256, 0, stream>>>(ei, cnt);
    k_scan_blk<<<64, 256, 0, stream>>>(cnt, pre, bsum);
    k_scan_top<<<1, 64, 0, stream>>>(bsum);
    k_scan_fix<<<N_NODES / 256, 256, 0, stream>>>(pre, bsum, row_ptr, coarse);
    k_bucket<<<256, 256, 0, stream>>>(ei, coarse, bpack, bsrc);
    k_sortp<<<256, 256, 0, stream>>>(bpack, bsrc, row_ptr, ea, M1, M2, ssrc, a1es, a2es);
    k_vh<<<N_NODES / 64, 256, 0, stream>>>(roi, roiWt, roib, x, g1Wt, g1as, g1ad, h1, a1s, a1d);
    k_sg1<<<N_NODES / 4, 256, 0, stream>>>(row_ptr, ssrc, a1s, a1d, a1es, h1, g1b, out1);
    k_h2<<<N_NODES / 64, 256, 0, stream>>>(out1, g2Wt, g2as, g2ad, h2b, a2s, a2d);
    k_sg2<<<N_NODES / 4, 256, 0, stream>>>(row_ptr, ssrc, a2s, a2d, a2es, h2b, g2b, hfin);
    k_pool<<<NB, 64, 0, stream>>>(bvec, hfin, gateW, gateb, scene, c1W, c1b, c2W, c2b, (float*)d_out);
}